// Round 4
// baseline (111.296 us; speedup 1.0000x reference)
//
#include <hip/hip_runtime.h>

// Bilateral filter denoiser: K=5, sigma_s=2.0, sigma_r=0.1, B=8,C=3,H=512,W=512, fp32.
// weight(dy,dx) = exp2( RC*(n-c)^2 + SL*(dy^2+dx^2) ), RC=-50*log2e, SL=-log2e/8.
// Exponent via 2 packed FMAs: arg = fma(fma(RC,n,B), n, Ck), B=-2RC*c, Ck=RC*c^2+SL*k.
// exp2 computed WITHOUT v_exp_f32 (trans pipe was ~2/3 of issue):
//   t = max(t,-30); z = t + 1.5*2^23 (RNE -> n=round(t), z_bits=0x4B400000+n,
//   low 9 bits of 0x4B400000 are 0 so (z_bits<<23)+bits(p) == p*2^n);
//   f = t-n in [-.5,.5]; p = deg-3 Taylor of 2^f (rel err ~6e-4 << 2e-2 threshold).
// All full-rate packed VALU: ~26 cyc/wave per 2-pixel tap vs ~40 with v_exp.
// 1 output row x 4 px per thread (R1/R2 geometry: spill-free, best measured).
// Center tap weight == 1 exactly -> ws init 1, acc init c; ws>=1 so rcp is safe.

#define KK 5
#define HALO 2
#define TX 64              // tile width (px)
#define TY 16              // tile height (px)
#define PXT 4              // px per thread along x
#define LW (TX + 2*HALO)   // 68 cols used
#define LH (TY + 2*HALO)   // 20 rows
#define LSTRIDE 72         // 16B-aligned rows; +8 banks/row shift
#define IMG_H 512
#define IMG_W 512

typedef float v2f __attribute__((ext_vector_type(2)));
typedef unsigned int uint32;

#if defined(__has_builtin) && __has_builtin(__builtin_amdgcn_rcpf)
#define FAST_RCP(x) __builtin_amdgcn_rcpf(x)
#else
#define FAST_RCP(x) (1.0f / (x))
#endif

__device__ __forceinline__ int reflect_idx(int i, int n) {
    i = (i < 0) ? -i : i;
    i = (i >= n) ? (2 * n - 2 - i) : i;
    return i;
}

__device__ __forceinline__ float scale2n(float p, float z) {
    // w = p * 2^n where z = n + 1.5*2^23 (bits: 0x4B400000 + n, low 9 bits of
    // the magic are zero, so (z_bits<<23) + p_bits adds n to p's exponent).
    uint32 zb = __builtin_bit_cast(uint32, z);
    uint32 pb = __builtin_bit_cast(uint32, p);
    return __builtin_bit_cast(float, (uint32)((zb << 23) + pb));
}

__global__ __launch_bounds__(256, 4)
void bilateral_kernel(const float* __restrict__ x, float* __restrict__ out) {
    __shared__ float tile[LH * LSTRIDE];

    const int tid = threadIdx.x;
    const int tileX0 = blockIdx.x * TX;
    const int tileY0 = blockIdx.y * TY;
    const int img = blockIdx.z;
    const float* __restrict__ src = x + (size_t)img * (IMG_H * IMG_W);
    float* __restrict__ dst = out + (size_t)img * (IMG_H * IMG_W);

    // ---- stage halo tile into LDS with reflect padding ----
    for (int idx = tid; idx < LH * LW; idx += 256) {
        int r = idx / LW;
        int c = idx - r * LW;
        int gy = reflect_idx(tileY0 - HALO + r, IMG_H);
        int gx = reflect_idx(tileX0 - HALO + c, IMG_W);
        tile[r * LSTRIDE + c] = src[gy * IMG_W + gx];
    }
    __syncthreads();

    const int txg = tid & 15;      // 0..15 -> x-group
    const int ty  = tid >> 4;      // 0..15 -> output row
    const int lx0 = txg * PXT;     // tile-local x (halo-frame col of window start)

    const float RC = -72.13475204444817f;     // -50 * log2(e)
    const float SL = -0.18033688011246232f;   // -log2(e) / 8
    const v2f RCv = {RC, RC};
    const v2f MAGIC = {12582912.0f, 12582912.0f};   // 1.5 * 2^23
    const v2f TMIN  = {-30.0f, -30.0f};
    const v2f P1v = {0.69314718056f, 0.69314718056f};
    const v2f P2v = {0.24022650696f, 0.24022650696f};
    const v2f P3v = {0.05550410866f, 0.05550410866f};
    const v2f ONE = {1.0f, 1.0f};

    // centers (halo coords: +HALO both axes)
    const float* crow = &tile[(ty + HALO) * LSTRIDE + lx0 + HALO];
    const v2f cA = {crow[0], crow[1]};
    const v2f cB = {crow[2], crow[3]};

    // per-pixel exponent-poly coefficients: arg = RC*v^2 + B*v + C0 (+ SL*k)
    const v2f BA = cA * (-2.0f * RC);
    const v2f BB = cB * (-2.0f * RC);
    const v2f C0A = (cA * cA) * RC;
    const v2f C0B = (cB * cB) * RC;

    // center tap folded in (weight exactly 1)
    v2f wsA = {1.0f, 1.0f}, wsB = {1.0f, 1.0f};
    v2f accA = cA, accB = cB;

    // one bilateral tap for a float2 pair: v=neighbors, Bc/Cc=exponent coeffs
    auto tap = [&](v2f v, v2f Bc, v2f Cc, v2f& ws, v2f& acc) {
        v2f t = __builtin_elementwise_fma(__builtin_elementwise_fma(RCv, v, Bc), v, Cc);
        t = __builtin_elementwise_max(t, TMIN);
        v2f z = t + MAGIC;                 // n = round(t) encoded in z's mantissa
        v2f f = t - (z - MAGIC);           // f in [-0.5, 0.5]
        v2f p = __builtin_elementwise_fma(f, P3v, P2v);
        p = __builtin_elementwise_fma(f, p, P1v);
        p = __builtin_elementwise_fma(f, p, ONE);
        v2f w;
        w.x = scale2n(p.x, z.x);
        w.y = scale2n(p.y, z.y);
        ws += w;
        acc = __builtin_elementwise_fma(w, v, acc);
    };

    #pragma unroll
    for (int dy = 0; dy < KK; dy++) {
        const float4* rp = reinterpret_cast<const float4*>(&tile[(ty + dy) * LSTRIDE + lx0]);
        const float4 f0 = rp[0];
        const float4 f1 = rp[1];
        const v2f P0 = {f0.x, f0.y}, P1 = {f0.z, f0.w}, P2 = {f1.x, f1.y}, P3 = {f1.z, f1.w};
        const v2f O0 = {f0.y, f0.z}, O1 = {f0.w, f1.x}, O2 = {f1.y, f1.z};

        const int dy2 = (dy - 2) * (dy - 2);
        const float k4 = SL * (float)(dy2 + 4);
        const float k1 = SL * (float)(dy2 + 1);
        const v2f C4A = C0A + k4, C1A_ = C0A + k1;
        const v2f C4B = C0B + k4, C1B_ = C0B + k1;

        tap(P0, BA, C4A,  wsA, accA);  tap(P1, BB, C4B,  wsB, accB);  // dx=0
        tap(O0, BA, C1A_, wsA, accA);  tap(O1, BB, C1B_, wsB, accB);  // dx=1
        if (dy2 != 0) {                                               // dx=2 (skip center)
            const float kz = SL * (float)dy2;
            const v2f CzA = C0A + kz, CzB = C0B + kz;
            tap(P1, BA, CzA, wsA, accA);  tap(P2, BB, CzB, wsB, accB);
        }
        tap(O1, BA, C1A_, wsA, accA);  tap(O2, BB, C1B_, wsB, accB);  // dx=3
        tap(P2, BA, C4A,  wsA, accA);  tap(P3, BB, C4B,  wsB, accB);  // dx=4
    }

    const int ox = tileX0 + lx0;
    const int oy = tileY0 + ty;
    float4 o;
    o.x = accA.x * FAST_RCP(wsA.x);   // ws >= 1 (center tap), clip is dead
    o.y = accA.y * FAST_RCP(wsA.y);
    o.z = accB.x * FAST_RCP(wsB.x);
    o.w = accB.y * FAST_RCP(wsB.y);
    *reinterpret_cast<float4*>(&dst[oy * IMG_W + ox]) = o;
}

extern "C" void kernel_launch(void* const* d_in, const int* in_sizes, int n_in,
                              void* d_out, int out_size, void* d_ws, size_t ws_size,
                              hipStream_t stream) {
    const float* x = (const float*)d_in[0];
    // d_in[1] (spatial 5x5) is analytically exp(-(dx^2+dy^2)/8); folded into constants.
    float* out = (float*)d_out;

    const int n_img = out_size / (IMG_H * IMG_W);   // B*C = 24
    dim3 grid(IMG_W / TX, IMG_H / TY, n_img);       // (8, 32, 24)
    dim3 block(256);
    hipLaunchKernelGGL(bilateral_kernel, grid, block, 0, stream, x, out);
}

// Round 5
// 105.049 us; speedup vs baseline: 1.0595x; 1.0595x over previous
//
#include <hip/hip_runtime.h>

// Bilateral filter denoiser: K=5, sigma_s=2.0, sigma_r=0.1, B=8,C=3,H=512,W=512, fp32.
// weight(dy,dx) = exp2( RC*(n-c)^2 + SL*(dy^2+dx^2) ), RC=-50*log2e, SL=-log2e/8.
// Exponent via 2 FMAs: arg = fma(fma(RC,n,B), n, Ck), B=-2RC*c, Ck=RC*c^2+SL*k.
// exp2 via magic-round + deg-3 poly + integer exponent add (no v_exp_f32).
// NO clamp needed: x in [0,1) -> t >= -73.6 -> n >= -74 -> result exponent >= 52 > 0.
// 2-px math forced onto the packed fp32 pipe with inline-asm v_pk_*_f32
// (R4 showed __builtin_elementwise_* on v2f scalarizes: issue stayed at ~33 us).
// Constants split SGPR/VGPR so each VOP3P has at most one SGPR source.
// Center tap weight == 1 exactly -> ws init 1, acc init c; ws>=1 so rcp is safe.

#define KK 5
#define HALO 2
#define TX 64              // tile width (px)
#define TY 16              // tile height (px)
#define PXT 4              // px per thread along x
#define LW (TX + 2*HALO)   // 68 cols used
#define LH (TY + 2*HALO)   // 20 rows
#define LSTRIDE 72         // 16B-aligned rows; +8 banks/row shift
#define IMG_H 512
#define IMG_W 512

typedef float v2f __attribute__((ext_vector_type(2)));
typedef unsigned int uint32;

#if defined(__has_builtin) && __has_builtin(__builtin_amdgcn_rcpf)
#define FAST_RCP(x) __builtin_amdgcn_rcpf(x)
#else
#define FAST_RCP(x) (1.0f / (x))
#endif

// ---- packed fp32 pipe (inline asm; "v" = VGPR pair, "s" = SGPR pair) ----
__device__ __forceinline__ v2f pk_fma_vvv(v2f a, v2f b, v2f c) {
    v2f d;
    asm("v_pk_fma_f32 %0, %1, %2, %3" : "=v"(d) : "v"(a), "v"(b), "v"(c));
    return d;
}
__device__ __forceinline__ v2f pk_fma_svv(v2f a, v2f b, v2f c) {
    v2f d;
    asm("v_pk_fma_f32 %0, %1, %2, %3" : "=v"(d) : "s"(a), "v"(b), "v"(c));
    return d;
}
__device__ __forceinline__ v2f pk_fma_vsv(v2f a, v2f b, v2f c) {
    v2f d;
    asm("v_pk_fma_f32 %0, %1, %2, %3" : "=v"(d) : "v"(a), "s"(b), "v"(c));
    return d;
}
__device__ __forceinline__ v2f pk_add_vv(v2f a, v2f b) {
    v2f d;
    asm("v_pk_add_f32 %0, %1, %2" : "=v"(d) : "v"(a), "v"(b));
    return d;
}
__device__ __forceinline__ v2f pk_add_vs(v2f a, v2f b) {
    v2f d;
    asm("v_pk_add_f32 %0, %1, %2" : "=v"(d) : "v"(a), "s"(b));
    return d;
}

__device__ __forceinline__ int reflect_idx(int i, int n) {
    i = (i < 0) ? -i : i;
    i = (i >= n) ? (2 * n - 2 - i) : i;
    return i;
}

__device__ __forceinline__ float scale2n(float p, float z) {
    // w = p * 2^n where z = n + 1.5*2^23; low 9 bits of the magic are zero so
    // (z_bits << 23) + p_bits adds n to p's exponent. Safe: n >= -74 here.
    uint32 zb = __builtin_bit_cast(uint32, z);
    uint32 pb = __builtin_bit_cast(uint32, p);
    return __builtin_bit_cast(float, (uint32)((zb << 23) + pb));
}

__global__ __launch_bounds__(256, 4)
void bilateral_kernel(const float* __restrict__ x, float* __restrict__ out) {
    __shared__ float tile[LH * LSTRIDE];

    const int tid = threadIdx.x;
    const int tileX0 = blockIdx.x * TX;
    const int tileY0 = blockIdx.y * TY;
    const int img = blockIdx.z;
    const float* __restrict__ src = x + (size_t)img * (IMG_H * IMG_W);
    float* __restrict__ dst = out + (size_t)img * (IMG_H * IMG_W);

    // ---- stage halo tile into LDS with reflect padding ----
    for (int idx = tid; idx < LH * LW; idx += 256) {
        int r = idx / LW;
        int c = idx - r * LW;
        int gy = reflect_idx(tileY0 - HALO + r, IMG_H);
        int gx = reflect_idx(tileX0 - HALO + c, IMG_W);
        tile[r * LSTRIDE + c] = src[gy * IMG_W + gx];
    }
    __syncthreads();

    const int txg = tid & 15;      // 0..15 -> x-group
    const int ty  = tid >> 4;      // 0..15 -> output row
    const int lx0 = txg * PXT;     // tile-local x (halo-frame col of window start)

    const float RC = -72.13475204444817f;     // -50 * log2(e)
    const float SL = -0.18033688011246232f;   // -log2(e) / 8

    // SGPR-resident packed constants (each pk instr uses at most one)
    const v2f RCs     = {RC, RC};
    const v2f MAGICs  = {12582912.0f, 12582912.0f};    // 1.5 * 2^23
    const v2f NMAGICs = {-12582912.0f, -12582912.0f};
    const v2f NONEs   = {-1.0f, -1.0f};
    const v2f P3s     = {0.05550410866f, 0.05550410866f};
    // VGPR-resident constants (addend slot alongside an SGPR source)
    const v2f P2v  = {0.24022650696f, 0.24022650696f};
    const v2f P1v  = {0.69314718056f, 0.69314718056f};
    const v2f ONEv = {1.0f, 1.0f};

    // centers (halo coords: +HALO both axes)
    const float* crow = &tile[(ty + HALO) * LSTRIDE + lx0 + HALO];
    const v2f cA = {crow[0], crow[1]};
    const v2f cB = {crow[2], crow[3]};

    // per-pixel exponent-poly coefficients: arg = RC*v^2 + B*v + C0 (+ SL*k)
    const v2f BA = cA * (-2.0f * RC);
    const v2f BB = cB * (-2.0f * RC);
    const v2f C0A = (cA * cA) * RC;
    const v2f C0B = (cB * cB) * RC;

    // center tap folded in (weight exactly 1)
    v2f wsA = {1.0f, 1.0f}, wsB = {1.0f, 1.0f};
    v2f accA = cA, accB = cB;

    // one bilateral tap for a float2 pixel pair (10 pk + 2 scalar VALU)
    auto tap = [&](v2f v, v2f Bc, v2f Cc, v2f& ws, v2f& acc) {
        v2f t = pk_fma_svv(RCs, v, Bc);      // RC*v + B          (sgpr: RC)
        t = pk_fma_vvv(t, v, Cc);            // t = RC*v^2+B*v+Ck
        v2f z = pk_add_vs(t, MAGICs);        // round(t) -> z     (sgpr: MAGIC)
        v2f nf = pk_add_vs(z, NMAGICs);      // nf = (float)n     (sgpr: NMAGIC)
        v2f f = pk_fma_vsv(nf, NONEs, t);    // f = t - n         (sgpr: NONE)
        v2f p = pk_fma_vsv(f, P3s, P2v);     // Horner deg-3      (sgpr: P3)
        p = pk_fma_vvv(f, p, P1v);
        p = pk_fma_vvv(f, p, ONEv);          // p ~= 2^f
        v2f w;
        w.x = scale2n(p.x, z.x);             // w = p * 2^n
        w.y = scale2n(p.y, z.y);
        ws = pk_add_vv(ws, w);
        acc = pk_fma_vvv(w, v, acc);
    };

    #pragma unroll
    for (int dy = 0; dy < KK; dy++) {
        const float4* rp = reinterpret_cast<const float4*>(&tile[(ty + dy) * LSTRIDE + lx0]);
        const float4 f0 = rp[0];
        const float4 f1 = rp[1];
        const v2f P0 = {f0.x, f0.y}, P1 = {f0.z, f0.w}, P2 = {f1.x, f1.y}, P3 = {f1.z, f1.w};
        const v2f O0 = {f0.y, f0.z}, O1 = {f0.w, f1.x}, O2 = {f1.y, f1.z};

        const int dy2 = (dy - 2) * (dy - 2);
        const float k4 = SL * (float)(dy2 + 4);
        const float k1 = SL * (float)(dy2 + 1);
        const v2f C4A = C0A + k4, C1A_ = C0A + k1;
        const v2f C4B = C0B + k4, C1B_ = C0B + k1;

        tap(P0, BA, C4A,  wsA, accA);  tap(P1, BB, C4B,  wsB, accB);  // dx=0
        tap(O0, BA, C1A_, wsA, accA);  tap(O1, BB, C1B_, wsB, accB);  // dx=1
        if (dy2 != 0) {                                               // dx=2 (skip center)
            const float kz = SL * (float)dy2;
            const v2f CzA = C0A + kz, CzB = C0B + kz;
            tap(P1, BA, CzA, wsA, accA);  tap(P2, BB, CzB, wsB, accB);
        }
        tap(O1, BA, C1A_, wsA, accA);  tap(O2, BB, C1B_, wsB, accB);  // dx=3
        tap(P2, BA, C4A,  wsA, accA);  tap(P3, BB, C4B,  wsB, accB);  // dx=4
    }

    const int ox = tileX0 + lx0;
    const int oy = tileY0 + ty;
    float4 o;
    o.x = accA.x * FAST_RCP(wsA.x);   // ws >= 1 (center tap), clip is dead
    o.y = accA.y * FAST_RCP(wsA.y);
    o.z = accB.x * FAST_RCP(wsB.x);
    o.w = accB.y * FAST_RCP(wsB.y);
    *reinterpret_cast<float4*>(&dst[oy * IMG_W + ox]) = o;
}

extern "C" void kernel_launch(void* const* d_in, const int* in_sizes, int n_in,
                              void* d_out, int out_size, void* d_ws, size_t ws_size,
                              hipStream_t stream) {
    const float* x = (const float*)d_in[0];
    // d_in[1] (spatial 5x5) is analytically exp(-(dx^2+dy^2)/8); folded into constants.
    float* out = (float*)d_out;

    const int n_img = out_size / (IMG_H * IMG_W);   // B*C = 24
    dim3 grid(IMG_W / TX, IMG_H / TY, n_img);       // (8, 32, 24)
    dim3 block(256);
    hipLaunchKernelGGL(bilateral_kernel, grid, block, 0, stream, x, out);
}